// Round 10
// baseline (350.658 us; speedup 1.0000x reference)
//
#include <hip/hip_runtime.h>
#include <hip/hip_cooperative_groups.h>

namespace cg = cooperative_groups;

#define N_NODES 100000
#define E_EDGES 2000000
#define SPLIT_E 1800000   // top 10%: 400k touches, P(node untouched) ~ e^-4 ~ 1.8%
#define CIN 16
#define EXH_FLOW 4.0f     // 0.0001 * 40000
#define TOP_E (E_EDGES - SPLIT_E)

#define UNROLL 4
#define ECHUNK (E_EDGES / UNROLL)          // 500000 edges per chunk
#define QTHREADS (E_EDGES * 4 / UNROLL)    // 2M work items: 4 lanes/edge, 4 edges/item

#define BLK 256
#define GRID_BLOCKS 1024                   // 4 blocks/CU on 256 CUs -> co-resident
#define TOTAL_THR (GRID_BLOCKS * BLK)      // 262144 (multiple of 4: lane role invariant)

// origin_data: (N, 8, 3) f32; last timestep at n*24 + {21,22,23} = {conc, people, size}
//
// Single cooperative dispatch, 4 phases / 3 grid syncs (replaces the serial
// 4-kernel chain; R9 evidence: remaining time was chain structure, not BW):
//   P1 table init -> P2 node-init + top-scatter (independent, co-scheduled)
//   -> P3 fused stream+scatter (R9's measured-best body) -> P4 finalize.
__global__ __launch_bounds__(BLK, 4) void mega_kernel(
        const float* __restrict__ origin,
        const float4* __restrict__ xv,
        const float* __restrict__ w,
        const float* __restrict__ b,
        const int* __restrict__ src,
        const int* __restrict__ dst,
        float* __restrict__ out,
        float* __restrict__ flow,
        int* __restrict__ max_ord,
        float* __restrict__ conc_c,
        float* __restrict__ rsize_c,
        unsigned char* __restrict__ settled) {
    cg::grid_group grid = cg::this_grid();
    const int tid = blockIdx.x * BLK + threadIdx.x;

    // ---- P1: table init (plain stores; memset nodes regressed R6, bitmap
    // atomics regressed R8 — byte-map + plain stores is the measured best).
    for (int n = tid; n < N_NODES; n += TOTAL_THR) {
        max_ord[n] = -1;
        settled[n] = 0;
    }
    grid.sync();

    // ---- P2: node init (needed only by P4) co-scheduled with top-chunk
    // scatter. Top chunk: pure atomics (values unsettled here; R2 lesson)
    // + settled marks via plain byte stores (same-value races benign).
    // Top orders >= 2*SPLIT_E dominate all lower orders -> marks are FINAL.
    for (int i = tid; i < N_NODES + TOP_E; i += TOTAL_THR) {
        if (i < N_NODES) {
            size_t base = (size_t)i * 24;
            float conc   = origin[base + 21];
            float people = origin[base + 22];
            float size   = origin[base + 23];
            float rs = 1.0f / size;
            out[i] = conc + EXH_FLOW * people * rs;
            conc_c[i]  = conc;
            rsize_c[i] = rs;
        } else {
            int e = SPLIT_E + (i - N_NODES);
            int s = src[e], d = dst[e];
            if (s != d) {
                atomicMax(&max_ord[s], 2 * e);
                atomicMax(&max_ord[d], 2 * e + 1);
                settled[s] = 1;
                settled[d] = 1;
            }
        }
    }
    grid.sync();

    // ---- P3: fused coalesced x-stream + leader-lane scatter (R9 body).
    // 4 lanes/edge, one float4 each (consecutive lanes -> consecutive 16B),
    // UNROLL-4 chunks for 4x outstanding loads; quad shfl_xor reduce (DPP).
    // Leader (q==0) stores flow (16/wave -> 64B contiguous) and pre-checks
    // the IMMUTABLE 100 KB settled byte-map (read-only here -> L2-hot;
    // ~66k firing atomics hit max_ord, a different array).
    {
        const int q = tid & 3;                       // invariant across stride
        const float4 wq = ((const float4*)w)[q];     // 64B total, L1 broadcast
        const float bias = b[0];
        for (int t = tid; t < QTHREADS; t += TOTAL_THR) {
            int e0 = t >> 2;                         // [0, ECHUNK)
            float4 v0 = xv[t + 0 * QTHREADS];
            float4 v1 = xv[t + 1 * QTHREADS];
            float4 v2 = xv[t + 2 * QTHREADS];
            float4 v3 = xv[t + 3 * QTHREADS];

            float p0 = v0.x * wq.x + v0.y * wq.y + v0.z * wq.z + v0.w * wq.w;
            float p1 = v1.x * wq.x + v1.y * wq.y + v1.z * wq.z + v1.w * wq.w;
            float p2 = v2.x * wq.x + v2.y * wq.y + v2.z * wq.z + v2.w * wq.w;
            float p3 = v3.x * wq.x + v3.y * wq.y + v3.z * wq.z + v3.w * wq.w;

            p0 += __shfl_xor(p0, 1);  p0 += __shfl_xor(p0, 2);
            p1 += __shfl_xor(p1, 1);  p1 += __shfl_xor(p1, 2);
            p2 += __shfl_xor(p2, 1);  p2 += __shfl_xor(p2, 2);
            p3 += __shfl_xor(p3, 1);  p3 += __shfl_xor(p3, 2);

            if (q == 0) {
                int ea = e0, eb = e0 + ECHUNK, ec = e0 + 2 * ECHUNK, ed = e0 + 3 * ECHUNK;
                flow[ea] = p0 + bias;
                flow[eb] = p1 + bias;
                flow[ec] = p2 + bias;
                flow[ed] = p3 + bias;
                int sa = src[ea], da = dst[ea];
                int sb = src[eb], db = dst[eb];
                int sc = src[ec], dc = dst[ec];
                int sd = src[ed], dd = dst[ed];
#define SCAT(EE, SS, DD)                                                  \
                if ((SS) != (DD)) {                                       \
                    if (!settled[SS]) atomicMax(&max_ord[SS], 2 * (EE));  \
                    if (!settled[DD]) atomicMax(&max_ord[DD], 2 * (EE) + 1); \
                }
                SCAT(ea, sa, da)
                SCAT(eb, sb, db)
                SCAT(ec, sc, dc)
                SCAT(ed, sd, dd)
#undef SCAT
            }
        }
    }
    grid.sync();

    // ---- P4: per-node finalize — decode winning occurrence, gather value.
    for (int n = tid; n < N_NODES; n += TOTAL_THR) {
        int o = max_ord[n];
        if (o < 0) continue;
        int e = o >> 1;
        float val = flow[e];
        float v;
        if ((o & 1) == 0) {
            v = val * conc_c[n] * rsize_c[n];        // src-side: src[e]==n
        } else {
            int s = src[e];
            v = val * conc_c[s] * rsize_c[n];        // dst-side
        }
        out[n] += v;
    }
}

extern "C" void kernel_launch(void* const* d_in, const int* in_sizes, int n_in,
                              void* d_out, int out_size, void* d_ws, size_t ws_size,
                              hipStream_t stream) {
    const float*  origin = (const float*)d_in[0];   // (N, 8, 3)
    const float4* xv     = (const float4*)d_in[1];  // (E, 1, 16) as 8M float4
    const float*  conv_w = (const float*)d_in[2];   // (1, 16, 1, 1)
    const float*  conv_b = (const float*)d_in[3];   // (1,)
    const int*    eidx   = (const int*)d_in[4];     // (2, E)
    const int* src = eidx;
    const int* dst = eidx + E_EDGES;

    float* out  = (float*)d_out;          // [0, N): result; [N, N+E): flow
    float* flow = out + N_NODES;

    int*           max_ord = (int*)d_ws;                           // 400 KB
    float*         conc_c  = (float*)((char*)d_ws + 1 * 400 * 1024);
    float*         rsize_c = (float*)((char*)d_ws + 2 * 400 * 1024);
    unsigned char* settled = (unsigned char*)((char*)d_ws + 3 * 400 * 1024); // 100 KB

    void* args[] = {
        (void*)&origin, (void*)&xv, (void*)&conv_w, (void*)&conv_b,
        (void*)&src, (void*)&dst, (void*)&out, (void*)&flow,
        (void*)&max_ord, (void*)&conc_c, (void*)&rsize_c, (void*)&settled
    };
    hipLaunchCooperativeKernel((void*)mega_kernel, dim3(GRID_BLOCKS), dim3(BLK),
                               args, 0, stream);
}

// Round 11
// 123.588 us; speedup vs baseline: 2.8373x; 2.8373x over previous
//
#include <hip/hip_runtime.h>

#define N_NODES 100000
#define E_EDGES 2000000
#define SPLIT_E 1800000   // top 10%: 400k touches, P(node untouched) ~ e^-4 ~ 1.8%
#define CIN 16
#define EXH_FLOW 4.0f     // 0.0001 * 40000
#define TOP_E (E_EDGES - SPLIT_E)

#define UNROLL 4
#define ECHUNK (E_EDGES / UNROLL)          // 500000 edges per chunk
#define QTHREADS (E_EDGES * 4 / UNROLL)    // 2M work items: 4 lanes/edge, 4 edges/item

#define BLK 256
#define TOP_BLOCKS ((TOP_E + BLK - 1) / BLK)          // 782
#define STREAM_BLOCKS ((QTHREADS + BLK - 1) / BLK)    // 7813

// origin_data: (N, 8, 3) f32; last timestep at n*24 + {21,22,23} = {conc, people, size}

// K1: node init + table init (in-kernel stores; memset nodes regressed R6,
// bitmap atomics regressed R8, cooperative persistent grid regressed R10).
__global__ void init_nodes_kernel(const float* __restrict__ origin,
                                  float* __restrict__ out,
                                  int* __restrict__ max_ord,
                                  float* __restrict__ conc_c,
                                  float* __restrict__ rsize_c,
                                  unsigned char* __restrict__ settled) {
    int n = blockIdx.x * blockDim.x + threadIdx.x;
    if (n >= N_NODES) return;
    size_t base = (size_t)n * 24;
    float conc   = origin[base + 21];
    float people = origin[base + 22];
    float size   = origin[base + 23];
    float rs = 1.0f / size;
    out[n] = conc + EXH_FLOW * people * rs;
    conc_c[n]  = conc;
    rsize_c[n] = rs;
    max_ord[n] = -1;
    settled[n] = 0;
}

// K2: merged {top-chunk scatter || fused stream+scatter} in ONE dispatch.
//
// Correctness under concurrency (no ordering needed between the two roles):
//  - atomicMax is commutative: any interleaving yields the same final max.
//  - settled pre-check is an OPTIMIZATION only. Stale 0 -> redundant atomic
//    whose order loses to the top-chunk order anyway. Read 1 -> the marking
//    thread's dominating atomicMax completes before this dispatch ends,
//    and finalize runs in a later dispatch.
//  - Only required orderings: init before this kernel; finalize after it.
//
// Top blocks FIRST (blockIdx < TOP_BLOCKS): 200k edges, pure atomics on
// max_ord (values unsettled; R2 lesson) + plain byte-store settled marks
// (same-value races benign; bitmap atomicOr regressed R8). They complete in
// the stream's first few us, so ~85% of stream checks still see the marks;
// the extra fired atomics ride the otherwise-idle atomic pipe under the
// BW-bound stream.
__global__ void fused_all_kernel(const float4* __restrict__ xv,
                                 const float* __restrict__ w,
                                 const float* __restrict__ b,
                                 const int* __restrict__ src,
                                 const int* __restrict__ dst,
                                 const unsigned char* __restrict__ settled_ro,
                                 unsigned char* __restrict__ settled_w,
                                 float* __restrict__ flow,
                                 int* __restrict__ max_ord) {
    if (blockIdx.x < TOP_BLOCKS) {
        int e = SPLIT_E + blockIdx.x * BLK + threadIdx.x;
        if (e >= E_EDGES) return;
        int s = src[e], d = dst[e];
        if (s != d) {
            atomicMax(&max_ord[s], 2 * e);
            atomicMax(&max_ord[d], 2 * e + 1);
            settled_w[s] = 1;
            settled_w[d] = 1;
        }
        return;
    }
    // Stream role: R9's measured-best body. 4 lanes/edge, one float4 each
    // (consecutive lanes -> consecutive 16B), UNROLL-4 chunks for 4x
    // outstanding loads; quad shfl_xor reduce. Leader (q==0) stores flow
    // (16/wave -> 64B contiguous) and pre-checks the immutable 100 KB
    // settled byte-map (L2-hot; firing atomics hit max_ord, not the map).
    int t = (blockIdx.x - TOP_BLOCKS) * BLK + threadIdx.x;   // [0, 2M)
    if (t >= QTHREADS) return;
    int q  = t & 3;
    int e0 = t >> 2;                      // [0, ECHUNK)
    float4 wq = ((const float4*)w)[q];    // 64B total, L1 broadcast
    float bias = b[0];

    float4 v0 = xv[t + 0 * QTHREADS];
    float4 v1 = xv[t + 1 * QTHREADS];
    float4 v2 = xv[t + 2 * QTHREADS];
    float4 v3 = xv[t + 3 * QTHREADS];

    float p0 = v0.x * wq.x + v0.y * wq.y + v0.z * wq.z + v0.w * wq.w;
    float p1 = v1.x * wq.x + v1.y * wq.y + v1.z * wq.z + v1.w * wq.w;
    float p2 = v2.x * wq.x + v2.y * wq.y + v2.z * wq.z + v2.w * wq.w;
    float p3 = v3.x * wq.x + v3.y * wq.y + v3.z * wq.z + v3.w * wq.w;

    p0 += __shfl_xor(p0, 1);  p0 += __shfl_xor(p0, 2);
    p1 += __shfl_xor(p1, 1);  p1 += __shfl_xor(p1, 2);
    p2 += __shfl_xor(p2, 1);  p2 += __shfl_xor(p2, 2);
    p3 += __shfl_xor(p3, 1);  p3 += __shfl_xor(p3, 2);

    if (q == 0) {
        int ea = e0, eb = e0 + ECHUNK, ec = e0 + 2 * ECHUNK, ed = e0 + 3 * ECHUNK;
        flow[ea] = p0 + bias;
        flow[eb] = p1 + bias;
        flow[ec] = p2 + bias;
        flow[ed] = p3 + bias;
        int sa = src[ea], da = dst[ea];
        int sb = src[eb], db = dst[eb];
        int sc = src[ec], dc = dst[ec];
        int sd = src[ed], dd = dst[ed];
#define SCAT(EE, SS, DD)                                                  \
        if ((SS) != (DD)) {                                               \
            if (!settled_ro[SS]) atomicMax(&max_ord[SS], 2 * (EE));       \
            if (!settled_ro[DD]) atomicMax(&max_ord[DD], 2 * (EE) + 1);   \
        }
        SCAT(ea, sa, da)
        SCAT(eb, sb, db)
        SCAT(ec, sc, dc)
        SCAT(ed, sd, dd)
#undef SCAT
    }
}

// K3: per-node finalize — decode winning occurrence, gather its value.
__global__ void finalize_kernel(const int* __restrict__ src,
                                const float* __restrict__ flow,
                                const int* __restrict__ max_ord,
                                const float* __restrict__ conc_c,
                                const float* __restrict__ rsize_c,
                                float* __restrict__ out) {
    int n = blockIdx.x * blockDim.x + threadIdx.x;
    if (n >= N_NODES) return;
    int o = max_ord[n];
    if (o < 0) return;
    int e = o >> 1;
    float val = flow[e];
    float v;
    if ((o & 1) == 0) {
        v = val * conc_c[n] * rsize_c[n];            // src-side: src[e]==n
    } else {
        int s = src[e];
        v = val * conc_c[s] * rsize_c[n];            // dst-side
    }
    out[n] += v;
}

extern "C" void kernel_launch(void* const* d_in, const int* in_sizes, int n_in,
                              void* d_out, int out_size, void* d_ws, size_t ws_size,
                              hipStream_t stream) {
    const float* origin = (const float*)d_in[0];   // (N, 8, 3)
    const float* x      = (const float*)d_in[1];   // (E, 1, 16)
    const float* conv_w = (const float*)d_in[2];   // (1, 16, 1, 1)
    const float* conv_b = (const float*)d_in[3];   // (1,)
    const int*   eidx   = (const int*)d_in[4];     // (2, E)
    const int* src = eidx;
    const int* dst = eidx + E_EDGES;

    float* out  = (float*)d_out;          // [0, N): result; [N, N+E): flow
    float* flow = out + N_NODES;

    int*           max_ord = (int*)d_ws;                           // 400 KB
    float*         conc_c  = (float*)((char*)d_ws + 1 * 400 * 1024);
    float*         rsize_c = (float*)((char*)d_ws + 2 * 400 * 1024);
    unsigned char* settled = (unsigned char*)((char*)d_ws + 3 * 400 * 1024); // 100 KB

    init_nodes_kernel<<<(N_NODES + BLK - 1) / BLK, BLK, 0, stream>>>(
        origin, out, max_ord, conc_c, rsize_c, settled);
    fused_all_kernel<<<TOP_BLOCKS + STREAM_BLOCKS, BLK, 0, stream>>>(
        (const float4*)x, conv_w, conv_b, src, dst, settled, settled, flow, max_ord);
    finalize_kernel<<<(N_NODES + BLK - 1) / BLK, BLK, 0, stream>>>(
        src, flow, max_ord, conc_c, rsize_c, out);
}

// Round 12
// 64.674 us; speedup vs baseline: 5.4219x; 1.9109x over previous
//
#include <hip/hip_runtime.h>

#define N_NODES 100000
#define E_EDGES 2000000
#define SPLIT_E 1800000   // top 10%: 400k touches, P(node untouched) ~ e^-4 ~ 1.8%
#define CIN 16
#define EXH_FLOW 4.0f     // 0.0001 * 40000
#define TOP_E (E_EDGES - SPLIT_E)

#define UNROLL 4
#define ECHUNK (E_EDGES / UNROLL)          // 500000 edges per chunk
#define QTHREADS (E_EDGES * 4 / UNROLL)    // 2M work items: 4 lanes/edge, 4 edges/item

#define BLK 256
#define NODE_BLOCKS ((N_NODES + BLK - 1) / BLK)   // 391
#define TOP_BLOCKS  ((TOP_E + BLK - 1) / BLK)     // 782

// origin_data: (N, 8, 3) f32; last timestep at n*24 + {21,22,23} = {conc, people, size}

// K0: table init only — wide int4 stores, ~512KB+100KB, ~2us. Must be a
// separate dispatch: top-chunk atomics may not race with these plain stores.
// (memset nodes cost 2 launches ~8us — R6; in-kernel is cheaper.)
__global__ void table_init_kernel(int4* __restrict__ max_ord4,
                                  uint4* __restrict__ settled4) {
    int i = blockIdx.x * blockDim.x + threadIdx.x;
    if (i < N_NODES / 4) max_ord4[i] = make_int4(-1, -1, -1, -1);
    if (i < N_NODES / 16) settled4[i] = make_uint4(0u, 0u, 0u, 0u);
}

// K1: node-init || top-chunk scatter as disjoint block ranges. The halves
// touch disjoint arrays (out/conc_c/rsize_c vs max_ord/settled) -> no
// ordering hazard; node-init (small stream) hides under top-scatter latency.
// Top chunk: pure atomics (values unsettled here; R2 lesson) + plain
// byte-store settled marks (same-value races benign; bitmap atomicOr
// regressed R8). Top orders >= 2*SPLIT_E dominate all lower orders ->
// marks are FINAL at this kernel's boundary.
__global__ void init_and_top_kernel(const float* __restrict__ origin,
                                    const int* __restrict__ src,
                                    const int* __restrict__ dst,
                                    float* __restrict__ out,
                                    float* __restrict__ conc_c,
                                    float* __restrict__ rsize_c,
                                    int* __restrict__ max_ord,
                                    unsigned char* __restrict__ settled) {
    if (blockIdx.x < NODE_BLOCKS) {
        int n = blockIdx.x * BLK + threadIdx.x;
        if (n >= N_NODES) return;
        size_t base = (size_t)n * 24;
        float conc   = origin[base + 21];
        float people = origin[base + 22];
        float size   = origin[base + 23];
        float rs = 1.0f / size;
        out[n] = conc + EXH_FLOW * people * rs;
        conc_c[n]  = conc;
        rsize_c[n] = rs;
    } else {
        int e = SPLIT_E + (blockIdx.x - NODE_BLOCKS) * BLK + threadIdx.x;
        if (e >= E_EDGES) return;
        int s = src[e], d = dst[e];
        if (s != d) {
            atomicMax(&max_ord[s], 2 * e);
            atomicMax(&max_ord[d], 2 * e + 1);
            settled[s] = 1;
            settled[d] = 1;
        }
    }
}

// K2: fused stream + ALL-LANE scatter. Stream: 4 lanes/edge, one float4 each
// (consecutive lanes -> consecutive 16B), UNROLL-4 chunks for 4x outstanding
// loads, quad shfl_xor reduce — after it ALL lanes hold p0..p3. Scatter is
// spread over the quartet (vs R9's leader-lane doing everything): lane q
// stores flow for chunk q (one wave store instruction covers the 4 64B
// segments) and handles side (q>>1) of chunks {(q&1), (q&1)+2} — per-lane
// dependent chain is 2 settled gathers, not 8. Pre-check target is the
// IMMUTABLE 100 KB byte-map (read-only in this dispatch -> L2-hot; R11
// proved immutability requires the kernel boundary). ~66k firing atomics
// hit max_ord, a different array.
__global__ void fused_flow_scatter_kernel(const float4* __restrict__ xv,
                                          const float* __restrict__ w,
                                          const float* __restrict__ b,
                                          const int* __restrict__ src,
                                          const int* __restrict__ dst,
                                          const unsigned char* __restrict__ settled,
                                          float* __restrict__ flow,
                                          int* __restrict__ max_ord) {
    int tid = blockIdx.x * blockDim.x + threadIdx.x;   // [0, 2M)
    if (tid >= QTHREADS) return;
    int q  = tid & 3;
    int e0 = tid >> 2;                    // [0, ECHUNK)
    float4 wq = ((const float4*)w)[q];    // 64B total, L1 broadcast
    float bias = b[0];

    float4 v0 = xv[tid + 0 * QTHREADS];
    float4 v1 = xv[tid + 1 * QTHREADS];
    float4 v2 = xv[tid + 2 * QTHREADS];
    float4 v3 = xv[tid + 3 * QTHREADS];

    float p0 = v0.x * wq.x + v0.y * wq.y + v0.z * wq.z + v0.w * wq.w;
    float p1 = v1.x * wq.x + v1.y * wq.y + v1.z * wq.z + v1.w * wq.w;
    float p2 = v2.x * wq.x + v2.y * wq.y + v2.z * wq.z + v2.w * wq.w;
    float p3 = v3.x * wq.x + v3.y * wq.y + v3.z * wq.z + v3.w * wq.w;

    p0 += __shfl_xor(p0, 1);  p0 += __shfl_xor(p0, 2);
    p1 += __shfl_xor(p1, 1);  p1 += __shfl_xor(p1, 2);
    p2 += __shfl_xor(p2, 1);  p2 += __shfl_xor(p2, 2);
    p3 += __shfl_xor(p3, 1);  p3 += __shfl_xor(p3, 2);

    // Flow store: lane q -> chunk q. Branchless select (static indexing only
    // — dynamic register indexing would spill to scratch).
    float pq = (q == 0) ? p0 : ((q == 1) ? p1 : ((q == 2) ? p2 : p3));
    flow[e0 + q * ECHUNK] = pq + bias;

    // Scatter side-tasks: side = q>>1 (0=src, 1=dst), chunks (q&1) and (q&1)+2.
    int side = q >> 1;
    int c1 = (q & 1), c2 = (q & 1) + 2;
    int ea = e0 + c1 * ECHUNK;
    int eb = e0 + c2 * ECHUNK;
    int sa = src[ea], da = dst[ea];
    int sb = src[eb], db = dst[eb];
    if (sa != da) {
        int idx = side ? da : sa;
        if (!settled[idx]) atomicMax(&max_ord[idx], 2 * ea + side);
    }
    if (sb != db) {
        int idx = side ? db : sb;
        if (!settled[idx]) atomicMax(&max_ord[idx], 2 * eb + side);
    }
}

// K3: per-node finalize — decode winning occurrence, gather its value.
__global__ void finalize_kernel(const int* __restrict__ src,
                                const float* __restrict__ flow,
                                const int* __restrict__ max_ord,
                                const float* __restrict__ conc_c,
                                const float* __restrict__ rsize_c,
                                float* __restrict__ out) {
    int n = blockIdx.x * blockDim.x + threadIdx.x;
    if (n >= N_NODES) return;
    int o = max_ord[n];
    if (o < 0) return;
    int e = o >> 1;
    float val = flow[e];
    float v;
    if ((o & 1) == 0) {
        v = val * conc_c[n] * rsize_c[n];            // src-side: src[e]==n
    } else {
        int s = src[e];
        v = val * conc_c[s] * rsize_c[n];            // dst-side
    }
    out[n] += v;
}

extern "C" void kernel_launch(void* const* d_in, const int* in_sizes, int n_in,
                              void* d_out, int out_size, void* d_ws, size_t ws_size,
                              hipStream_t stream) {
    const float* origin = (const float*)d_in[0];   // (N, 8, 3)
    const float* x      = (const float*)d_in[1];   // (E, 1, 16)
    const float* conv_w = (const float*)d_in[2];   // (1, 16, 1, 1)
    const float* conv_b = (const float*)d_in[3];   // (1,)
    const int*   eidx   = (const int*)d_in[4];     // (2, E)
    const int* src = eidx;
    const int* dst = eidx + E_EDGES;

    float* out  = (float*)d_out;          // [0, N): result; [N, N+E): flow
    float* flow = out + N_NODES;

    int*           max_ord = (int*)d_ws;                           // 400 KB
    float*         conc_c  = (float*)((char*)d_ws + 1 * 400 * 1024);
    float*         rsize_c = (float*)((char*)d_ws + 2 * 400 * 1024);
    unsigned char* settled = (unsigned char*)((char*)d_ws + 3 * 400 * 1024); // 100 KB

    table_init_kernel<<<(N_NODES / 4 + BLK - 1) / BLK, BLK, 0, stream>>>(
        (int4*)max_ord, (uint4*)settled);
    init_and_top_kernel<<<NODE_BLOCKS + TOP_BLOCKS, BLK, 0, stream>>>(
        origin, src, dst, out, conc_c, rsize_c, max_ord, settled);
    fused_flow_scatter_kernel<<<(QTHREADS + BLK - 1) / BLK, BLK, 0, stream>>>(
        (const float4*)x, conv_w, conv_b, src, dst, settled, flow, max_ord);
    finalize_kernel<<<(N_NODES + BLK - 1) / BLK, BLK, 0, stream>>>(
        src, flow, max_ord, conc_c, rsize_c, out);
}